// Round 16
// baseline (172.753 us; speedup 1.0000x reference)
//
#include <hip/hip_runtime.h>
#include <hip/hip_bf16.h>

typedef __hip_bfloat16 bf16;
typedef __attribute__((ext_vector_type(4))) float f32x4;
typedef __attribute__((ext_vector_type(8))) short s16x8;
typedef __attribute__((ext_vector_type(4))) short s16x4;
typedef __attribute__((ext_vector_type(4))) int i32x4;

#define QSCALE 0.18033688f  // 0.125 * log2(e): attention scale + exp2 folding

__device__ __forceinline__ void gld_lds16(const void* g, void* l) {
  __builtin_amdgcn_global_load_lds(
      (const __attribute__((address_space(1))) unsigned int*)g,
      (__attribute__((address_space(3))) unsigned int*)l, 16, 0, 0);
}

__device__ __forceinline__ short bf16bits(float f) {
  bf16 h = __float2bfloat16(f);
  return *reinterpret_cast<short*>(&h);
}

__device__ __forceinline__ unsigned bf16pack(float lo, float hi) {
  return ((unsigned)(unsigned short)bf16bits(hi) << 16) |
         (unsigned)(unsigned short)bf16bits(lo);
}

// K/V weight-column permutation: n=(h,d) -> r*128 + (h>>3)*64 + d, r=h&7
__device__ __forceinline__ int kvperm(int n) {
  return ((n >> 6) & 7) * 128 + (n >> 9) * 64 + (n & 63);
}

// ---------------- mask scan: pos/srcrow/cnt per pattern ----------------
__global__ __launch_bounds__(64) void mask_scan(const int* __restrict__ mask,
                                                int* __restrict__ pos_tab,
                                                int* __restrict__ srcrow,
                                                int* __restrict__ cnt) {
  int r = blockIdx.x;
  const int* mr = mask + r * 1024;
  int lane = threadIdx.x;
  int loc[16];
  int c = 0;
#pragma unroll
  for (int i = 0; i < 16; i++) {
    loc[i] = (mr[lane * 16 + i] == 0) ? 1 : 0;
    c += loc[i];
  }
  int inc = c;
#pragma unroll
  for (int off = 1; off < 64; off <<= 1) {
    int v = __shfl_up(inc, off);
    if (lane >= off) inc += v;
  }
  int running = inc - c;
#pragma unroll
  for (int i = 0; i < 16; i++) {
    pos_tab[r * 1024 + lane * 16 + i] = loc[i] ? running : -1;
    if (loc[i]) srcrow[r * 1024 + running] = lane * 16 + i;
    running += loc[i];
  }
  if (lane == 63) cnt[r] = inc;
}

// ---------------- fused prep: cvt h/l, 5 weight transposes, bias, tail-zero ----
__global__ __launch_bounds__(256) void prep(
    const float* __restrict__ h, const float* __restrict__ l,
    const float* __restrict__ Wq, const float* __restrict__ Wk,
    const float* __restrict__ Wv, const float* __restrict__ Wo,
    const float* __restrict__ Wl,
    const float* __restrict__ bq, const float* __restrict__ bk,
    const float* __restrict__ bv, const int* __restrict__ mask,
    bf16* __restrict__ hb, bf16* __restrict__ lb,
    bf16* __restrict__ WqkvT, bf16* __restrict__ WoT, bf16* __restrict__ WlT,
    float* __restrict__ bqkv,
    bf16* __restrict__ kc, bf16* __restrict__ vTc) {
  const int blk = blockIdx.x, tid = threadIdx.x;
  __shared__ float tile[32][33];
  __shared__ int cnt_sh;

  if (blk < 9216) {
    const float* in = (blk < 8192) ? h : l;
    bf16* out = (blk < 8192) ? hb : lb;
    int base = (blk < 8192) ? blk : (blk - 8192);
    int i = (base * 256 + tid) * 4;
    float4 v = *reinterpret_cast<const float4*>(in + i);
    s16x4 o;
    o[0] = bf16bits(v.x); o[1] = bf16bits(v.y);
    o[2] = bf16bits(v.z); o[3] = bf16bits(v.w);
    *reinterpret_cast<s16x4*>(out + i) = o;
  } else if (blk < 13440) {
    const float* W; bf16* Wt; int K = 1024, N = 1024, rowofs = 0, perm = 0, b2;
    float scale = 1.f;
    if (blk < 10240)      { W = Wq; Wt = WqkvT; b2 = blk - 9216;  scale = QSCALE; }
    else if (blk < 11264) { W = Wk; Wt = WqkvT; b2 = blk - 10240; perm = 1; rowofs = 1024; }
    else if (blk < 12288) { W = Wv; Wt = WqkvT; b2 = blk - 11264; perm = 1; rowofs = 2048; }
    else if (blk < 13312) { W = Wo; Wt = WoT;   b2 = blk - 12288; }
    else                  { W = Wl; Wt = WlT;   b2 = blk - 13312; K = 128; }
    int gx = (K == 128) ? (b2 & 3) : (b2 & 31);
    int gy = (K == 128) ? (b2 >> 2) : (b2 >> 5);
    int k0 = gx * 32, n0 = gy * 32;
    int tx = tid & 31, ty = tid >> 5;
    for (int i = ty; i < 32; i += 8) tile[i][tx] = W[(size_t)(k0 + i) * N + n0 + tx];
    __syncthreads();
    for (int i = ty; i < 32; i += 8) {
      int nn = n0 + i;
      int orow = perm ? (rowofs + kvperm(nn)) : (rowofs + nn);
      Wt[(size_t)orow * K + k0 + tx] = __float2bfloat16(tile[tx][i] * scale);
    }
  } else if (blk < 13444) {
    int n = (blk - 13440) * 256 + tid;
    if (n < 1024) {
      bqkv[n] = bq[n] * QSCALE;
      int pr = kvperm(n);
      bqkv[1024 + pr] = bk[n];
      bqkv[2048 + pr] = bv[n];
    }
  } else {
    int bh = blk - 13444;
    if (tid == 0) cnt_sh = 0;
    __syncthreads();
    const int* mr = mask + (bh & 7) * 1024;
    int c = 0;
    for (int i = tid; i < 1024; i += 256) c += (mr[i] == 0) ? 1 : 0;
    c += __shfl_xor(c, 1);  c += __shfl_xor(c, 2);  c += __shfl_xor(c, 4);
    c += __shfl_xor(c, 8);  c += __shfl_xor(c, 16); c += __shfl_xor(c, 32);
    if ((tid & 63) == 0) atomicAdd(&cnt_sh, c);
    __syncthreads();
    int cc = cnt_sh;
    int e = (cc + 63) & ~63;
    bf16 z = __float2bfloat16(0.f);
    bf16* kb = kc + (size_t)bh * 1024 * 128;
    for (int i = tid; i < 64 * 128; i += 256) {
      int rr = cc + (i >> 7);
      if (rr < e) kb[(size_t)rr * 128 + (i & 127)] = z;
    }
    bf16* vb = vTc + (size_t)bh * 64 * 1024;
    for (int i = tid; i < 64 * 64; i += 256) {
      int dv = i >> 6, col = cc + (i & 63);
      if (col < e) vb[(size_t)dv * 1024 + col] = z;
    }
  }
}

// ---------------- merged QKV+L GEMM (3-deep pipeline, counted vmcnt) ----------------
__global__ __launch_bounds__(256) void gemm_qkv(
    const bf16* __restrict__ A, const bf16* __restrict__ Bt,
    const bf16* __restrict__ lb, const bf16* __restrict__ WlT,
    const float* __restrict__ bias, const float* __restrict__ bl,
    const int* __restrict__ srcrow, const int* __restrict__ cnt_g,
    const int* __restrict__ pos_tab,
    bf16* __restrict__ qcat, bf16* __restrict__ kc, bf16* __restrict__ vTc) {
  __shared__ bf16 Alds[3][128 * 32];
  __shared__ bf16 Blds[3][128 * 32];
  __shared__ int pos_l[2][128];
  const int nt = blockIdx.y;
  const int g = nt >> 3;
  const int r = nt & 7;
  const int tid = threadIdx.x;
  const int lane = tid & 63, wv = tid >> 6;
  const int wm = wv >> 1, wn = wv & 1;
  const int rlo = lane & 15, kgp = lane >> 4;
  const int srow = tid >> 2, ssl = tid & 3;

  const bf16* Ap;
  const bf16* Bp;
  int lda_, ldb_, nk;
  if (g == 3) {
    Ap = lb; lda_ = 128; nk = 4;
    Bp = WlT + (size_t)r * 128 * 128; ldb_ = 128;
  } else {
    Ap = A; lda_ = 1024; nk = 32;
    Bp = Bt + (size_t)nt * 128 * 1024; ldb_ = 1024;
  }

  int mrow0, mrow1, b = 0, basep = 0, vcnt = 128;
  if (g == 0 || g == 3) {
    int bm = blockIdx.x * 128;
    mrow0 = bm + srow;
    mrow1 = bm + 64 + srow;
    if (g == 3) {
      int h0 = r * 2;
      int hs = tid >> 7, sl = tid & 127;
      pos_l[hs][sl] = pos_tab[((h0 + hs) & 7) * 1024 + (bm & 1023) + sl];
    }
  } else {
    b = blockIdx.x & 7;
    basep = (blockIdx.x >> 3) * 128;
    int cr = cnt_g[r];
    if (basep >= cr) return;
    vcnt = min(128, cr - basep);
    int p0 = min(basep + srow, cr - 1);
    int p1 = min(basep + 64 + srow, cr - 1);
    mrow0 = b * 1024 + srcrow[r * 1024 + p0];
    mrow1 = b * 1024 + srcrow[r * 1024 + p1];
  }

  f32x4 acc[4][4];
#pragma unroll
  for (int i = 0; i < 4; i++)
#pragma unroll
    for (int j = 0; j < 4; j++) acc[i][j] = (f32x4){0.f, 0.f, 0.f, 0.f};

  const int gslA = ssl ^ ((srow >> 1) & 3);

  auto STAGE = [&](int buf, int kt) {
    char* Ad = (char*)Alds[buf];
    char* Bd = (char*)Blds[buf];
    gld_lds16(Ap + (size_t)mrow0 * lda_ + kt + gslA * 8, Ad + tid * 16);
    gld_lds16(Ap + (size_t)mrow1 * lda_ + kt + gslA * 8, Ad + (256 + tid) * 16);
    gld_lds16(Bp + (size_t)srow * ldb_ + kt + gslA * 8, Bd + tid * 16);
    gld_lds16(Bp + (size_t)(64 + srow) * ldb_ + kt + gslA * 8, Bd + (256 + tid) * 16);
  };

  STAGE(0, 0);
  STAGE(1, 32);
  int cur = 0;
#pragma unroll 1
  for (int ti = 0; ti < nk; ti++) {
    if (ti < nk - 1) {
      asm volatile("s_waitcnt vmcnt(4)" ::: "memory");
    } else {
      asm volatile("s_waitcnt vmcnt(0)" ::: "memory");
    }
    __syncthreads();
    if (ti + 2 < nk) {
      int b2 = cur + 2;
      if (b2 >= 3) b2 -= 3;
      STAGE(b2, (ti + 2) * 32);
    }

    char* Ab = (char*)Alds[cur];
    char* Bb = (char*)Blds[cur];
    s16x8 afr[4], bfr[4];
#pragma unroll
    for (int mi = 0; mi < 4; mi++) {
      int row = wm * 64 + mi * 16 + rlo;
      int ps = kgp ^ ((row >> 1) & 3);
      afr[mi] = *(const s16x8*)(Ab + row * 64 + ps * 16);
    }
#pragma unroll
    for (int ni = 0; ni < 4; ni++) {
      int row = wn * 64 + ni * 16 + rlo;
      int ps = kgp ^ ((row >> 1) & 3);
      bfr[ni] = *(const s16x8*)(Bb + row * 64 + ps * 16);
    }
#pragma unroll
    for (int mi = 0; mi < 4; mi++)
#pragma unroll
      for (int ni = 0; ni < 4; ni++)
        acc[mi][ni] = __builtin_amdgcn_mfma_f32_16x16x32_bf16(afr[mi], bfr[ni], acc[mi][ni], 0, 0, 0);
    cur = (cur == 2) ? 0 : cur + 1;
  }

  if (g == 0 || g == 3) {
#pragma unroll
    for (int mi = 0; mi < 4; mi++) {
#pragma unroll
      for (int ni = 0; ni < 4; ni++) {
        int nl = wn * 64 + ni * 16 + rlo;
        int ncol = r * 128 + nl;
        float bv = (g == 3) ? bl[ncol] : bias[nt * 128 + nl];
        int hh = ncol >> 6, d = ncol & 63, hs = nl >> 6;
        int dof = (g == 3) ? 64 : 0;
#pragma unroll
        for (int reg = 0; reg < 4; reg++) {
          int ml = wm * 64 + mi * 16 + kgp * 4 + reg;
          int m = blockIdx.x * 128 + ml;
          int b0 = m >> 10, s = m & 1023;
          float v = acc[mi][ni][reg] + bv;
          v = v > 0.f ? v : 0.f;
          size_t hbase = (size_t)(b0 * 16 + hh) * 1024;
          float vq = (g == 3) ? v * QSCALE : v;
          qcat[(hbase + s) * 128 + dof + d] = __float2bfloat16(vq);
          if (g == 3) {
            int p = pos_l[hs][ml];
            if (p >= 0) kc[(hbase + p) * 128 + 64 + d] = __float2bfloat16(v);
          }
        }
      }
    }
  } else {
#pragma unroll
    for (int mi = 0; mi < 4; mi++) {
#pragma unroll
      for (int ni = 0; ni < 4; ni++) {
        int nl = wn * 64 + ni * 16 + rlo;
        float bv = bias[nt * 128 + nl];
        int hbit = nl >> 6, d = nl & 63;
        int hh = hbit * 8 + r;
#pragma unroll
        for (int reg = 0; reg < 4; reg++) {
          int ml = wm * 64 + mi * 16 + kgp * 4 + reg;
          float v = acc[mi][ni][reg] + bv;
          v = v > 0.f ? v : 0.f;
          bf16 vb = __float2bfloat16(v);
          int p = basep + ml;
          if (ml < vcnt) {
            if (g == 1)
              kc[((size_t)(b * 16 + hh) * 1024 + p) * 128 + d] = vb;
            else
              vTc[((size_t)(b * 16 + hh) * 64 + d) * 1024 + p] = vb;
          }
        }
      }
    }
  }
}

// ---------------- O-projection GEMM: relu + column-reduce, 2-phase ----------------
__global__ __launch_bounds__(256) void gemm_oproj(
    const bf16* __restrict__ A, const bf16* __restrict__ Bt,
    const float* __restrict__ bias, float* __restrict__ out) {
  __shared__ bf16 Alds[2][128 * 32];
  __shared__ bf16 Blds[2][128 * 32];
  const int tid = threadIdx.x;
  const int lane = tid & 63, wv = tid >> 6;
  const int wm = wv >> 1, wn = wv & 1;
  const int bm = blockIdx.x * 128, bn = blockIdx.y * 128;
  const int rlo = lane & 15, kgp = lane >> 4;

  f32x4 acc[4][4];
#pragma unroll
  for (int i = 0; i < 4; i++)
#pragma unroll
    for (int j = 0; j < 4; j++) acc[i][j] = (f32x4){0.f, 0.f, 0.f, 0.f};

  const int srow = tid >> 2, ssl = tid & 3;

  auto STAGE = [&](int buf, int kt) {
    char* Ad = (char*)Alds[buf];
    char* Bd = (char*)Blds[buf];
#pragma unroll
    for (int rr = 0; rr < 2; ++rr) {
      int row = rr * 64 + srow;
      int gsl = ssl ^ ((row >> 1) & 3);
      gld_lds16(A + (size_t)(bm + row) * 1024 + kt + gsl * 8, Ad + (rr * 256 + tid) * 16);
      gld_lds16(Bt + (size_t)(bn + row) * 1024 + kt + gsl * 8, Bd + (rr * 256 + tid) * 16);
    }
  };

  STAGE(0, 0);
  int cur = 0;
#pragma unroll 1
  for (int kt = 0; kt < 1024; kt += 32) {
    asm volatile("s_waitcnt vmcnt(0)" ::: "memory");
    __syncthreads();
    if (kt + 32 < 1024) STAGE(cur ^ 1, kt + 32);

    char* Ab = (char*)Alds[cur];
    char* Bb = (char*)Blds[cur];
    s16x8 afr[4], bfr[4];
#pragma unroll
    for (int mi = 0; mi < 4; mi++) {
      int row = wm * 64 + mi * 16 + rlo;
      int ps = kgp ^ ((row >> 1) & 3);
      afr[mi] = *(const s16x8*)(Ab + row * 64 + ps * 16);
    }
#pragma unroll
    for (int ni = 0; ni < 4; ni++) {
      int row = wn * 64 + ni * 16 + rlo;
      int ps = kgp ^ ((row >> 1) & 3);
      bfr[ni] = *(const s16x8*)(Bb + row * 64 + ps * 16);
    }
#pragma unroll
    for (int mi = 0; mi < 4; mi++)
#pragma unroll
      for (int ni = 0; ni < 4; ni++)
        acc[mi][ni] = __builtin_amdgcn_mfma_f32_16x16x32_bf16(afr[mi], bfr[ni], acc[mi][ni], 0, 0, 0);
    cur ^= 1;
  }

  int b = bm >> 10;
  float cs[4];
#pragma unroll
  for (int ni = 0; ni < 4; ni++) {
    int n = bn + wn * 64 + ni * 16 + rlo;
    float bv = bias[n];
    float sum = 0.f;
#pragma unroll
    for (int mi = 0; mi < 4; mi++)
#pragma unroll
      for (int reg = 0; reg < 4; reg++) {
        float v = acc[mi][ni][reg] + bv;
        sum += (v > 0.f ? v : 0.f);
      }
    cs[ni] = sum;
  }
#pragma unroll
  for (int ni = 0; ni < 4; ni++) {
    cs[ni] += __shfl_xor(cs[ni], 16);
    cs[ni] += __shfl_xor(cs[ni], 32);
  }
  if (lane < 16) {
#pragma unroll
    for (int ni = 0; ni < 4; ni++) {
      int n = bn + wn * 64 + ni * 16 + lane;
      atomicAdd(out + b * 1024 + n, cs[ni]);
      atomicAdd(out + 8192 + b * 1024 + n, cs[ni]);
    }
  }
}

// ---------------- flash attention: QBLK=128, 8 waves; swapped QK^T ->
// register-resident P (no LDS P buffer), max-free exp2 softmax ----
// mfma(K,Q) gives S^T: lane holds P[q=rlo][key=ni*16+kgp*4+reg]. The PV
// A-frag (keys kgp*8+2dw,+1 of each 32-key slice) is assembled by static
// cross-lane remap: srcLane = rlo+16*((2*kgp+(dw>>1))&3), src dword dw&1,
// register dpk[2*kk2+(kgp>>1)] (two shfls + select; reg idx is lane-dep).
// PV output layout (rows kgp*4+reg, cols rlo) matches oacc unchanged.
__global__ __launch_bounds__(512) void attn_kernel(
    const bf16* __restrict__ qcat, const bf16* __restrict__ kc,
    const bf16* __restrict__ vTc, const int* __restrict__ cnt_g,
    bf16* __restrict__ ybuf) {
  __shared__ char Klds[2][64 * 256];
  __shared__ char Vlds[2][64 * 128];
  const int id = blockIdx.x;
  const int qt = (id >> 3) & 7;
  const int bh = (id & 7) * 16 + (id >> 6);
  const int tid = threadIdx.x, lane = tid & 63, wv = tid >> 6;
  const int b = bh >> 4, hh = bh & 15;
  const int rlo = lane & 15, kgp = lane >> 4;
  const bf16* qp = qcat + (size_t)bh * 1024 * 128;
  const bf16* kp = kc + (size_t)bh * 1024 * 128;
  const bf16* vp = vTc + (size_t)bh * 64 * 1024;
  const int cnt = cnt_g[bh & 7];

  s16x8 qf[4];
  {
    int qrow = qt * 128 + wv * 16 + rlo;
#pragma unroll
    for (int kk = 0; kk < 4; kk++)
      qf[kk] = *(const s16x8*)(qp + (size_t)qrow * 128 + kk * 32 + kgp * 8);
  }
  s16x8 onesf;
#pragma unroll
  for (int i = 0; i < 8; i++) onesf[i] = (short)0x3F80;  // bf16(1.0)

  // PV remap constants (per-lane invariant)
  int srcl[4];
#pragma unroll
  for (int dw = 0; dw < 4; dw++) srcl[dw] = rlo + 16 * ((2 * kgp + (dw >> 1)) & 3);
  const bool loHalf = (kgp < 2);

  f32x4 oacc[5];  // [0..3]=dv fragments, [4]=row-sum (ones column)
#pragma unroll
  for (int i = 0; i < 5; i++) oacc[i] = (f32x4){0.f, 0.f, 0.f, 0.f};

  auto STAGE = [&](int buf, int t0) {
#pragma unroll
    for (int r = 0; r < 2; r++) {
      int c = r * 512 + tid, row = c >> 4, sl = c & 15, gsl = sl ^ (row & 7);
      gld_lds16(kp + (size_t)(t0 + row) * 128 + gsl * 8, Klds[buf] + c * 16);
    }
    {
      int c = tid, dv = c >> 3, sl = c & 7, gsl = sl ^ (dv & 7);
      gld_lds16(vp + (size_t)dv * 1024 + t0 + gsl * 8, Vlds[buf] + c * 16);
    }
  };

  auto COMPUTE = [&](int buf, int t0) {
    char* Kb = Klds[buf];
    char* Vb = Vlds[buf];
    f32x4 scT[4];
#pragma unroll
    for (int i = 0; i < 4; i++) scT[i] = (f32x4){0.f, 0.f, 0.f, 0.f};
    __builtin_amdgcn_s_setprio(1);
#pragma unroll
    for (int kk = 0; kk < 4; kk++) {
#pragma unroll
      for (int ni = 0; ni < 4; ni++) {
        int row = ni * 16 + rlo;
        int ps = (kk * 4 + kgp) ^ (row & 7);
        s16x8 kf = *(const s16x8*)(Kb + row * 256 + ps * 16);
        // swapped operands: S^T = K * Q^T (same reads, transposed output)
        scT[ni] = __builtin_amdgcn_mfma_f32_16x16x32_bf16(kf, qf[kk], scT[ni], 0, 0, 0);
      }
    }
    __builtin_amdgcn_s_setprio(0);

    // P = exp2(score); tail keys (>= cnt) masked to 0 (zeroed K rows give
    // score 0 -> exp2=1 otherwise). Key index = t0 + ni*16 + kgp*4 + reg.
    const bool tail = (t0 + 64 > cnt);
    unsigned dpk[4][2];
#pragma unroll
    for (int ni = 0; ni < 4; ni++) {
      float p0, p1, p2, p3;
      if (!tail) {
        p0 = exp2f(scT[ni][0]); p1 = exp2f(scT[ni][1]);
        p2 = exp2f(scT[ni][2]); p3 = exp2f(scT[ni][3]);
      } else {
        int kb = t0 + ni * 16 + kgp * 4;
        p0 = (kb + 0 < cnt) ? exp2f(scT[ni][0]) : 0.f;
        p1 = (kb + 1 < cnt) ? exp2f(scT[ni][1]) : 0.f;
        p2 = (kb + 2 < cnt) ? exp2f(scT[ni][2]) : 0.f;
        p3 = (kb + 3 < cnt) ? exp2f(scT[ni][3]) : 0.f;
      }
      dpk[ni][0] = bf16pack(p0, p1);
      dpk[ni][1] = bf16pack(p2, p3);
    }

    // PV + ones-column rowsum; A-frag via cross-lane remap
    __builtin_amdgcn_s_setprio(1);
#pragma unroll
    for (int kk2 = 0; kk2 < 2; kk2++) {
      i32x4 pa_i;
#pragma unroll
      for (int dw = 0; dw < 4; dw++) {
        int va = __shfl((int)dpk[2 * kk2][dw & 1], srcl[dw]);
        int vb = __shfl((int)dpk[2 * kk2 + 1][dw & 1], srcl[dw]);
        pa_i[dw] = loHalf ? va : vb;
      }
      s16x8 pa = *reinterpret_cast<s16x8*>(&pa_i);
#pragma unroll
      for (int n = 0; n < 4; n++) {
        int dv = n * 16 + rlo;
        int voff = dv * 128 + ((kk2 * 64 + kgp * 16) ^ ((dv & 7) << 4));
        s16x8 vfr = *(const s16x8*)(Vb + voff);
        oacc[n] = __builtin_amdgcn_mfma_f32_16x16x32_bf16(pa, vfr, oacc[n], 0, 0, 0);
      }
      oacc[4] = __builtin_amdgcn_mfma_f32_16x16x32_bf16(pa, onesf, oacc[4], 0, 0, 0);
    }
    __builtin_amdgcn_s_setprio(0);
  };

  STAGE(0, 0);
  int cur = 0;
#pragma unroll 1
  for (int t0 = 0; t0 < cnt; t0 += 64) {
    asm volatile("s_waitcnt vmcnt(0)" ::: "memory");
    __syncthreads();
    if (t0 + 64 < cnt) STAGE(cur ^ 1, t0 + 64);
    COMPUTE(cur, t0);
    cur ^= 1;
  }

  int sbase = qt * 128 + wv * 16;
#pragma unroll
  for (int n = 0; n < 4; n++) {
#pragma unroll
    for (int reg = 0; reg < 4; reg++) {
      int srow = sbase + kgp * 4 + reg;
      int col = hh * 64 + n * 16 + rlo;
      float y = oacc[n][reg] / oacc[4][reg];
      ybuf[((size_t)b * 1024 + srow) * 1024 + col] = __float2bfloat16(y);
    }
  }
}

// ---------------- launcher ----------------
extern "C" void kernel_launch(void* const* d_in, const int* in_sizes, int n_in,
                              void* d_out, int out_size, void* d_ws, size_t ws_size,
                              hipStream_t stream) {
  const float* h = (const float*)d_in[0];
  const int* mask = (const int*)d_in[1];
  const float* l = (const float*)d_in[3];
  const float* Wq = (const float*)d_in[4];
  const float* bq = (const float*)d_in[5];
  const float* Wk = (const float*)d_in[6];
  const float* bk = (const float*)d_in[7];
  const float* Wv = (const float*)d_in[8];
  const float* bv = (const float*)d_in[9];
  const float* Wl = (const float*)d_in[12];
  const float* bl = (const float*)d_in[13];
  const float* Wo = (const float*)d_in[14];
  const float* bo = (const float*)d_in[15];
  float* out = (float*)d_out;
  char* ws = (char*)d_ws;

  bf16* hb = (bf16*)(ws + 0);                    // 16 MB (reused as ybuf)
  bf16* lb = (bf16*)(ws + 16777216);             // 2 MB
  bf16* WqkvT = (bf16*)(ws + 18874368);          // 6 MB [3072][1024]
  bf16* WoT = (bf16*)(ws + 25165824);            // 2 MB
  bf16* WlT = (bf16*)(ws + 27262976);            // 256 KB
  float* bqkv = (float*)(ws + 27525120);         // 12 KB
  bf16* qcat = (bf16*)(ws + 27537408);           // 32 MB
  bf16* kcatc = (bf16*)(ws + 61091840);          // 32 MB
  bf16* vTc = (bf16*)(ws + 94646272);            // 16 MB
  int* pos_tab = (int*)(ws + 111423488);         // 32 KB
  int* srcrow = (int*)(ws + 111456256);          // 32 KB
  int* cnt = (int*)(ws + 111489024);             // 32 B
  bf16* ybuf = hb;

  prep<<<13572, 256, 0, stream>>>(h, l, Wq, Wk, Wv, Wo, Wl, bq, bk, bv, mask,
                                  hb, lb, WqkvT, WoT, WlT, bqkv, kcatc, vTc);
  mask_scan<<<8, 64, 0, stream>>>(mask, pos_tab, srcrow, cnt);

  gemm_qkv<<<dim3(64, 32), 256, 0, stream>>>(hb, WqkvT, lb, WlT, bqkv, bl,
                                             srcrow, cnt, pos_tab,
                                             qcat, kcatc, vTc);

  attn_kernel<<<1024, 512, 0, stream>>>(qcat, kcatc, vTc, cnt, ybuf);

  hipMemsetAsync(d_out, 0, (size_t)out_size * sizeof(float), stream);
  gemm_oproj<<<dim3(64, 8), 256, 0, stream>>>(ybuf, WoT, bo, out);
}

// Round 17
// 169.695 us; speedup vs baseline: 1.0180x; 1.0180x over previous
//
#include <hip/hip_runtime.h>
#include <hip/hip_bf16.h>

typedef __hip_bfloat16 bf16;
typedef __attribute__((ext_vector_type(4))) float f32x4;
typedef __attribute__((ext_vector_type(8))) short s16x8;
typedef __attribute__((ext_vector_type(4))) short s16x4;

#define QSCALE 0.18033688f  // 0.125 * log2(e): attention scale + exp2 folding

__device__ __forceinline__ void gld_lds16(const void* g, void* l) {
  __builtin_amdgcn_global_load_lds(
      (const __attribute__((address_space(1))) unsigned int*)g,
      (__attribute__((address_space(3))) unsigned int*)l, 16, 0, 0);
}

__device__ __forceinline__ short bf16bits(float f) {
  bf16 h = __float2bfloat16(f);
  return *reinterpret_cast<short*>(&h);
}

__device__ __forceinline__ int psw(int row) {
  return ((row & 7) << 4) ^ ((row & 8) << 2);
}

// K/V weight-column permutation: n=(h,d) -> r*128 + (h>>3)*64 + d, r=h&7
__device__ __forceinline__ int kvperm(int n) {
  return ((n >> 6) & 7) * 128 + (n >> 9) * 64 + (n & 63);
}

// ---------------- mask scan: pos/srcrow/cnt per pattern ----------------
__global__ __launch_bounds__(64) void mask_scan(const int* __restrict__ mask,
                                                int* __restrict__ pos_tab,
                                                int* __restrict__ srcrow,
                                                int* __restrict__ cnt) {
  int r = blockIdx.x;
  const int* mr = mask + r * 1024;
  int lane = threadIdx.x;
  int loc[16];
  int c = 0;
#pragma unroll
  for (int i = 0; i < 16; i++) {
    loc[i] = (mr[lane * 16 + i] == 0) ? 1 : 0;
    c += loc[i];
  }
  int inc = c;
#pragma unroll
  for (int off = 1; off < 64; off <<= 1) {
    int v = __shfl_up(inc, off);
    if (lane >= off) inc += v;
  }
  int running = inc - c;
#pragma unroll
  for (int i = 0; i < 16; i++) {
    pos_tab[r * 1024 + lane * 16 + i] = loc[i] ? running : -1;
    if (loc[i]) srcrow[r * 1024 + running] = lane * 16 + i;
    running += loc[i];
  }
  if (lane == 63) cnt[r] = inc;
}

// ---------------- fused prep: cvt h/l, 5 weight transposes, bias, tail-zero ----
// block ranges: [0,8192) cvt h | [8192,9216) cvt l | [9216,10240) Wq (scaled)
// [10240,11264) Wk | [11264,12288) Wv | [12288,13312) Wo | [13312,13440) Wl
// [13440,13444) bias | [13444,13572) tail_zero (computes its OWN cnt from mask
// so prep is independent of mask_scan and can launch first)
__global__ __launch_bounds__(256) void prep(
    const float* __restrict__ h, const float* __restrict__ l,
    const float* __restrict__ Wq, const float* __restrict__ Wk,
    const float* __restrict__ Wv, const float* __restrict__ Wo,
    const float* __restrict__ Wl,
    const float* __restrict__ bq, const float* __restrict__ bk,
    const float* __restrict__ bv, const int* __restrict__ mask,
    bf16* __restrict__ hb, bf16* __restrict__ lb,
    bf16* __restrict__ WqkvT, bf16* __restrict__ WoT, bf16* __restrict__ WlT,
    float* __restrict__ bqkv,
    bf16* __restrict__ kc, bf16* __restrict__ vTc) {
  const int blk = blockIdx.x, tid = threadIdx.x;
  __shared__ float tile[32][33];
  __shared__ int cnt_sh;

  if (blk < 9216) {
    const float* in = (blk < 8192) ? h : l;
    bf16* out = (blk < 8192) ? hb : lb;
    int base = (blk < 8192) ? blk : (blk - 8192);
    int i = (base * 256 + tid) * 4;
    float4 v = *reinterpret_cast<const float4*>(in + i);
    s16x4 o;
    o[0] = bf16bits(v.x); o[1] = bf16bits(v.y);
    o[2] = bf16bits(v.z); o[3] = bf16bits(v.w);
    *reinterpret_cast<s16x4*>(out + i) = o;
  } else if (blk < 13440) {
    const float* W; bf16* Wt; int K = 1024, N = 1024, rowofs = 0, perm = 0, b2;
    float scale = 1.f;
    if (blk < 10240)      { W = Wq; Wt = WqkvT; b2 = blk - 9216;  scale = QSCALE; }
    else if (blk < 11264) { W = Wk; Wt = WqkvT; b2 = blk - 10240; perm = 1; rowofs = 1024; }
    else if (blk < 12288) { W = Wv; Wt = WqkvT; b2 = blk - 11264; perm = 1; rowofs = 2048; }
    else if (blk < 13312) { W = Wo; Wt = WoT;   b2 = blk - 12288; }
    else                  { W = Wl; Wt = WlT;   b2 = blk - 13312; K = 128; }
    int gx = (K == 128) ? (b2 & 3) : (b2 & 31);
    int gy = (K == 128) ? (b2 >> 2) : (b2 >> 5);
    int k0 = gx * 32, n0 = gy * 32;
    int tx = tid & 31, ty = tid >> 5;
    for (int i = ty; i < 32; i += 8) tile[i][tx] = W[(size_t)(k0 + i) * N + n0 + tx];
    __syncthreads();
    for (int i = ty; i < 32; i += 8) {
      int nn = n0 + i;
      int orow = perm ? (rowofs + kvperm(nn)) : (rowofs + nn);
      Wt[(size_t)orow * K + k0 + tx] = __float2bfloat16(tile[tx][i] * scale);
    }
  } else if (blk < 13444) {
    int n = (blk - 13440) * 256 + tid;
    if (n < 1024) {
      bqkv[n] = bq[n] * QSCALE;
      int pr = kvperm(n);
      bqkv[1024 + pr] = bk[n];
      bqkv[2048 + pr] = bv[n];
    }
  } else {
    int bh = blk - 13444;
    // count zeros of this head-pattern's mask row (independent of mask_scan)
    if (tid == 0) cnt_sh = 0;
    __syncthreads();
    const int* mr = mask + (bh & 7) * 1024;
    int c = 0;
    for (int i = tid; i < 1024; i += 256) c += (mr[i] == 0) ? 1 : 0;
    c += __shfl_xor(c, 1);  c += __shfl_xor(c, 2);  c += __shfl_xor(c, 4);
    c += __shfl_xor(c, 8);  c += __shfl_xor(c, 16); c += __shfl_xor(c, 32);
    if ((tid & 63) == 0) atomicAdd(&cnt_sh, c);
    __syncthreads();
    int cc = cnt_sh;
    int e = (cc + 63) & ~63;
    bf16 z = __float2bfloat16(0.f);
    bf16* kb = kc + (size_t)bh * 1024 * 128;
    for (int i = tid; i < 64 * 128; i += 256) {
      int rr = cc + (i >> 7);
      if (rr < e) kb[(size_t)rr * 128 + (i & 127)] = z;
    }
    bf16* vb = vTc + (size_t)bh * 64 * 1024;
    for (int i = tid; i < 64 * 64; i += 256) {
      int dv = i >> 6, col = cc + (i & 63);
      if (col < e) vb[(size_t)dv * 1024 + col] = z;
    }
  }
}

// ---------------- merged QKV+L GEMM (3-deep pipeline, counted vmcnt) ----------------
// grid (64, 32). g = nt>>3: 0=Q, 1=K, 2=V (compacted gather; b=x&7, basep=(x>>3)*128),
// 3=L (A=lb, K=128): qcat copy scaled by QSCALE (attention+exp2 folding), kcat unscaled.
__global__ __launch_bounds__(256) void gemm_qkv(
    const bf16* __restrict__ A, const bf16* __restrict__ Bt,
    const bf16* __restrict__ lb, const bf16* __restrict__ WlT,
    const float* __restrict__ bias, const float* __restrict__ bl,
    const int* __restrict__ srcrow, const int* __restrict__ cnt_g,
    const int* __restrict__ pos_tab,
    bf16* __restrict__ qcat, bf16* __restrict__ kc, bf16* __restrict__ vTc) {
  __shared__ bf16 Alds[3][128 * 32];
  __shared__ bf16 Blds[3][128 * 32];
  __shared__ int pos_l[2][128];
  const int nt = blockIdx.y;
  const int g = nt >> 3;
  const int r = nt & 7;
  const int tid = threadIdx.x;
  const int lane = tid & 63, wv = tid >> 6;
  const int wm = wv >> 1, wn = wv & 1;
  const int rlo = lane & 15, kgp = lane >> 4;
  const int srow = tid >> 2, ssl = tid & 3;

  const bf16* Ap;
  const bf16* Bp;
  int lda_, ldb_, nk;
  if (g == 3) {
    Ap = lb; lda_ = 128; nk = 4;
    Bp = WlT + (size_t)r * 128 * 128; ldb_ = 128;
  } else {
    Ap = A; lda_ = 1024; nk = 32;
    Bp = Bt + (size_t)nt * 128 * 1024; ldb_ = 1024;
  }

  int mrow0, mrow1, b = 0, basep = 0, vcnt = 128;
  if (g == 0 || g == 3) {
    int bm = blockIdx.x * 128;
    mrow0 = bm + srow;
    mrow1 = bm + 64 + srow;
    if (g == 3) {
      int h0 = r * 2;
      int hs = tid >> 7, sl = tid & 127;
      pos_l[hs][sl] = pos_tab[((h0 + hs) & 7) * 1024 + (bm & 1023) + sl];
    }
  } else {
    b = blockIdx.x & 7;
    basep = (blockIdx.x >> 3) * 128;
    int cr = cnt_g[r];
    if (basep >= cr) return;
    vcnt = min(128, cr - basep);
    int p0 = min(basep + srow, cr - 1);
    int p1 = min(basep + 64 + srow, cr - 1);
    mrow0 = b * 1024 + srcrow[r * 1024 + p0];
    mrow1 = b * 1024 + srcrow[r * 1024 + p1];
  }

  f32x4 acc[4][4];
#pragma unroll
  for (int i = 0; i < 4; i++)
#pragma unroll
    for (int j = 0; j < 4; j++) acc[i][j] = (f32x4){0.f, 0.f, 0.f, 0.f};

  const int gslA = ssl ^ ((srow >> 1) & 3);

  auto STAGE = [&](int buf, int kt) {
    char* Ad = (char*)Alds[buf];
    char* Bd = (char*)Blds[buf];
    gld_lds16(Ap + (size_t)mrow0 * lda_ + kt + gslA * 8, Ad + tid * 16);
    gld_lds16(Ap + (size_t)mrow1 * lda_ + kt + gslA * 8, Ad + (256 + tid) * 16);
    gld_lds16(Bp + (size_t)srow * ldb_ + kt + gslA * 8, Bd + tid * 16);
    gld_lds16(Bp + (size_t)(64 + srow) * ldb_ + kt + gslA * 8, Bd + (256 + tid) * 16);
  };

  STAGE(0, 0);
  STAGE(1, 32);
  int cur = 0;
#pragma unroll 1
  for (int ti = 0; ti < nk; ti++) {
    if (ti < nk - 1) {
      asm volatile("s_waitcnt vmcnt(4)" ::: "memory");
    } else {
      asm volatile("s_waitcnt vmcnt(0)" ::: "memory");
    }
    __syncthreads();
    if (ti + 2 < nk) {
      int b2 = cur + 2;
      if (b2 >= 3) b2 -= 3;
      STAGE(b2, (ti + 2) * 32);
    }

    char* Ab = (char*)Alds[cur];
    char* Bb = (char*)Blds[cur];
    s16x8 afr[4], bfr[4];
#pragma unroll
    for (int mi = 0; mi < 4; mi++) {
      int row = wm * 64 + mi * 16 + rlo;
      int ps = kgp ^ ((row >> 1) & 3);
      afr[mi] = *(const s16x8*)(Ab + row * 64 + ps * 16);
    }
#pragma unroll
    for (int ni = 0; ni < 4; ni++) {
      int row = wn * 64 + ni * 16 + rlo;
      int ps = kgp ^ ((row >> 1) & 3);
      bfr[ni] = *(const s16x8*)(Bb + row * 64 + ps * 16);
    }
#pragma unroll
    for (int mi = 0; mi < 4; mi++)
#pragma unroll
      for (int ni = 0; ni < 4; ni++)
        acc[mi][ni] = __builtin_amdgcn_mfma_f32_16x16x32_bf16(afr[mi], bfr[ni], acc[mi][ni], 0, 0, 0);
    cur = (cur == 2) ? 0 : cur + 1;
  }

  if (g == 0 || g == 3) {
#pragma unroll
    for (int mi = 0; mi < 4; mi++) {
#pragma unroll
      for (int ni = 0; ni < 4; ni++) {
        int nl = wn * 64 + ni * 16 + rlo;
        int ncol = r * 128 + nl;
        float bv = (g == 3) ? bl[ncol] : bias[nt * 128 + nl];
        int hh = ncol >> 6, d = ncol & 63, hs = nl >> 6;
        int dof = (g == 3) ? 64 : 0;
#pragma unroll
        for (int reg = 0; reg < 4; reg++) {
          int ml = wm * 64 + mi * 16 + kgp * 4 + reg;
          int m = blockIdx.x * 128 + ml;
          int b0 = m >> 10, s = m & 1023;
          float v = acc[mi][ni][reg] + bv;
          v = v > 0.f ? v : 0.f;
          size_t hbase = (size_t)(b0 * 16 + hh) * 1024;
          float vq = (g == 3) ? v * QSCALE : v;
          qcat[(hbase + s) * 128 + dof + d] = __float2bfloat16(vq);
          if (g == 3) {
            int p = pos_l[hs][ml];
            if (p >= 0) kc[(hbase + p) * 128 + 64 + d] = __float2bfloat16(v);
          }
        }
      }
    }
  } else {
#pragma unroll
    for (int mi = 0; mi < 4; mi++) {
#pragma unroll
      for (int ni = 0; ni < 4; ni++) {
        int nl = wn * 64 + ni * 16 + rlo;
        float bv = bias[nt * 128 + nl];
        int hbit = nl >> 6, d = nl & 63;
        int hh = hbit * 8 + r;
#pragma unroll
        for (int reg = 0; reg < 4; reg++) {
          int ml = wm * 64 + mi * 16 + kgp * 4 + reg;
          float v = acc[mi][ni][reg] + bv;
          v = v > 0.f ? v : 0.f;
          bf16 vb = __float2bfloat16(v);
          int p = basep + ml;
          if (ml < vcnt) {
            if (g == 1)
              kc[((size_t)(b * 16 + hh) * 1024 + p) * 128 + d] = vb;
            else
              vTc[((size_t)(b * 16 + hh) * 64 + d) * 1024 + p] = vb;
          }
        }
      }
    }
  }
}

// ---------------- O-projection GEMM: relu + column-reduce, 2-phase ----------------
__global__ __launch_bounds__(256) void gemm_oproj(
    const bf16* __restrict__ A, const bf16* __restrict__ Bt,
    const float* __restrict__ bias, float* __restrict__ out) {
  __shared__ bf16 Alds[2][128 * 32];
  __shared__ bf16 Blds[2][128 * 32];
  const int tid = threadIdx.x;
  const int lane = tid & 63, wv = tid >> 6;
  const int wm = wv >> 1, wn = wv & 1;
  const int bm = blockIdx.x * 128, bn = blockIdx.y * 128;
  const int rlo = lane & 15, kgp = lane >> 4;

  f32x4 acc[4][4];
#pragma unroll
  for (int i = 0; i < 4; i++)
#pragma unroll
    for (int j = 0; j < 4; j++) acc[i][j] = (f32x4){0.f, 0.f, 0.f, 0.f};

  const int srow = tid >> 2, ssl = tid & 3;

  auto STAGE = [&](int buf, int kt) {
    char* Ad = (char*)Alds[buf];
    char* Bd = (char*)Blds[buf];
#pragma unroll
    for (int rr = 0; rr < 2; ++rr) {
      int row = rr * 64 + srow;
      int gsl = ssl ^ ((row >> 1) & 3);
      gld_lds16(A + (size_t)(bm + row) * 1024 + kt + gsl * 8, Ad + (rr * 256 + tid) * 16);
      gld_lds16(Bt + (size_t)(bn + row) * 1024 + kt + gsl * 8, Bd + (rr * 256 + tid) * 16);
    }
  };

  STAGE(0, 0);
  int cur = 0;
#pragma unroll 1
  for (int kt = 0; kt < 1024; kt += 32) {
    asm volatile("s_waitcnt vmcnt(0)" ::: "memory");
    __syncthreads();
    if (kt + 32 < 1024) STAGE(cur ^ 1, kt + 32);

    char* Ab = (char*)Alds[cur];
    char* Bb = (char*)Blds[cur];
    s16x8 afr[4], bfr[4];
#pragma unroll
    for (int mi = 0; mi < 4; mi++) {
      int row = wm * 64 + mi * 16 + rlo;
      int ps = kgp ^ ((row >> 1) & 3);
      afr[mi] = *(const s16x8*)(Ab + row * 64 + ps * 16);
    }
#pragma unroll
    for (int ni = 0; ni < 4; ni++) {
      int row = wn * 64 + ni * 16 + rlo;
      int ps = kgp ^ ((row >> 1) & 3);
      bfr[ni] = *(const s16x8*)(Bb + row * 64 + ps * 16);
    }
#pragma unroll
    for (int mi = 0; mi < 4; mi++)
#pragma unroll
      for (int ni = 0; ni < 4; ni++)
        acc[mi][ni] = __builtin_amdgcn_mfma_f32_16x16x32_bf16(afr[mi], bfr[ni], acc[mi][ni], 0, 0, 0);
    cur ^= 1;
  }

  int b = bm >> 10;
  float cs[4];
#pragma unroll
  for (int ni = 0; ni < 4; ni++) {
    int n = bn + wn * 64 + ni * 16 + rlo;
    float bv = bias[n];
    float sum = 0.f;
#pragma unroll
    for (int mi = 0; mi < 4; mi++)
#pragma unroll
      for (int reg = 0; reg < 4; reg++) {
        float v = acc[mi][ni][reg] + bv;
        sum += (v > 0.f ? v : 0.f);
      }
    cs[ni] = sum;
  }
#pragma unroll
  for (int ni = 0; ni < 4; ni++) {
    cs[ni] += __shfl_xor(cs[ni], 16);
    cs[ni] += __shfl_xor(cs[ni], 32);
  }
  if (lane < 16) {
#pragma unroll
    for (int ni = 0; ni < 4; ni++) {
      int n = bn + wn * 64 + ni * 16 + lane;
      atomicAdd(out + b * 1024 + n, cs[ni]);
      atomicAdd(out + 8192 + b * 1024 + n, cs[ni]);
    }
  }
}

// ---------------- flash attention: QBLK=128, 8 waves; NO max tracking ----
// Softmax is scale-invariant: P = exp2(score) raw (scores bounded |s| <~ 30
// base-2 units << f32 exp range), rowsum via ones-column MFMA, final divide
// cancels the missing normalization exactly. Tail keys masked to P=0.
__global__ __launch_bounds__(512) void attn_kernel(
    const bf16* __restrict__ qcat, const bf16* __restrict__ kc,
    const bf16* __restrict__ vTc, const int* __restrict__ cnt_g,
    bf16* __restrict__ ybuf) {
  __shared__ char Klds[2][64 * 256];
  __shared__ char Vlds[2][64 * 128];
  __shared__ char Plds[8][16 * 128];
  const int id = blockIdx.x;
  const int qt = (id >> 3) & 7;
  const int bh = (id & 7) * 16 + (id >> 6);
  const int tid = threadIdx.x, lane = tid & 63, wv = tid >> 6;
  const int b = bh >> 4, hh = bh & 15;
  const int rlo = lane & 15, kgp = lane >> 4;
  const bf16* qp = qcat + (size_t)bh * 1024 * 128;
  const bf16* kp = kc + (size_t)bh * 1024 * 128;
  const bf16* vp = vTc + (size_t)bh * 64 * 1024;
  const int cnt = cnt_g[bh & 7];

  s16x8 qf[4];
  {
    int qrow = qt * 128 + wv * 16 + rlo;
#pragma unroll
    for (int kk = 0; kk < 4; kk++)
      qf[kk] = *(const s16x8*)(qp + (size_t)qrow * 128 + kk * 32 + kgp * 8);
  }
  s16x8 onesf;
#pragma unroll
  for (int i = 0; i < 8; i++) onesf[i] = (short)0x3F80;  // bf16(1.0)

  f32x4 oacc[5];  // [0..3]=dv fragments, [4]=row-sum (ones column)
#pragma unroll
  for (int i = 0; i < 5; i++) oacc[i] = (f32x4){0.f, 0.f, 0.f, 0.f};
  char* pb = Plds[wv];

  auto STAGE = [&](int buf, int t0) {
#pragma unroll
    for (int r = 0; r < 2; r++) {
      int c = r * 512 + tid, row = c >> 4, sl = c & 15, gsl = sl ^ (row & 7);
      gld_lds16(kp + (size_t)(t0 + row) * 128 + gsl * 8, Klds[buf] + c * 16);
    }
    {
      int c = tid, dv = c >> 3, sl = c & 7, gsl = sl ^ (dv & 7);
      gld_lds16(vp + (size_t)dv * 1024 + t0 + gsl * 8, Vlds[buf] + c * 16);
    }
  };

  auto COMPUTE = [&](int buf, int t0) {
    char* Kb = Klds[buf];
    char* Vb = Vlds[buf];
    f32x4 sc[4];
#pragma unroll
    for (int i = 0; i < 4; i++) sc[i] = (f32x4){0.f, 0.f, 0.f, 0.f};
    __builtin_amdgcn_s_setprio(1);
#pragma unroll
    for (int kk = 0; kk < 4; kk++) {
#pragma unroll
      for (int ni = 0; ni < 4; ni++) {
        int row = ni * 16 + rlo;
        int ps = (kk * 4 + kgp) ^ (row & 7);
        s16x8 kf = *(const s16x8*)(Kb + row * 256 + ps * 16);
        sc[ni] = __builtin_amdgcn_mfma_f32_16x16x32_bf16(qf[kk], kf, sc[ni], 0, 0, 0);
      }
    }
    __builtin_amdgcn_s_setprio(0);

    // P = exp2(score) raw -- no max tracking (see header comment)
    const bool tail = (t0 + 64 > cnt);
    float p[4][4];
    if (!tail) {
#pragma unroll
      for (int ni = 0; ni < 4; ni++)
#pragma unroll
        for (int reg = 0; reg < 4; reg++) p[ni][reg] = exp2f(sc[ni][reg]);
    } else {
#pragma unroll
      for (int ni = 0; ni < 4; ni++) {
        bool ok = (t0 + ni * 16 + rlo) < cnt;
#pragma unroll
        for (int reg = 0; reg < 4; reg++)
          p[ni][reg] = ok ? exp2f(sc[ni][reg]) : 0.f;
      }
    }

    // P -> per-wave LDS (bf16, conflict-free swizzle)
#pragma unroll
    for (int ni = 0; ni < 4; ni++) {
#pragma unroll
      for (int reg = 0; reg < 4; reg++) {
        int row = kgp * 4 + reg;
        int off = row * 128 + ((ni * 32 + rlo * 2) ^ psw(row));
        *(bf16*)(pb + off) = __float2bfloat16(p[ni][reg]);
      }
    }
    asm volatile("s_waitcnt lgkmcnt(0)" ::: "memory");
    __builtin_amdgcn_sched_barrier(0);

    // PV + ones-column rowsum
    __builtin_amdgcn_s_setprio(1);
#pragma unroll
    for (int kk2 = 0; kk2 < 2; kk2++) {
      int poff = rlo * 128 + ((kk2 * 64 + kgp * 16) ^ psw(rlo));
      s16x8 pa = *(const s16x8*)(pb + poff);
#pragma unroll
      for (int n = 0; n < 4; n++) {
        int dv = n * 16 + rlo;
        int voff = dv * 128 + ((kk2 * 64 + kgp * 16) ^ ((dv & 7) << 4));
        s16x8 vfr = *(const s16x8*)(Vb + voff);
        oacc[n] = __builtin_amdgcn_mfma_f32_16x16x32_bf16(pa, vfr, oacc[n], 0, 0, 0);
      }
      oacc[4] = __builtin_amdgcn_mfma_f32_16x16x32_bf16(pa, onesf, oacc[4], 0, 0, 0);
    }
    __builtin_amdgcn_s_setprio(0);
  };

  STAGE(0, 0);
  int cur = 0;
#pragma unroll 1
  for (int t0 = 0; t0 < cnt; t0 += 64) {
    asm volatile("s_waitcnt vmcnt(0)" ::: "memory");
    __syncthreads();
    if (t0 + 64 < cnt) STAGE(cur ^ 1, t0 + 64);
    COMPUTE(cur, t0);
    cur ^= 1;
  }

  int sbase = qt * 128 + wv * 16;
#pragma unroll
  for (int n = 0; n < 4; n++) {
#pragma unroll
    for (int reg = 0; reg < 4; reg++) {
      int srow = sbase + kgp * 4 + reg;
      int col = hh * 64 + n * 16 + rlo;
      float y = oacc[n][reg] / oacc[4][reg];
      ybuf[((size_t)b * 1024 + srow) * 1024 + col] = __float2bfloat16(y);
    }
  }
}

// ---------------- launcher ----------------
extern "C" void kernel_launch(void* const* d_in, const int* in_sizes, int n_in,
                              void* d_out, int out_size, void* d_ws, size_t ws_size,
                              hipStream_t stream) {
  const float* h = (const float*)d_in[0];
  const int* mask = (const int*)d_in[1];
  const float* l = (const float*)d_in[3];
  const float* Wq = (const float*)d_in[4];
  const float* bq = (const float*)d_in[5];
  const float* Wk = (const float*)d_in[6];
  const float* bk = (const float*)d_in[7];
  const float* Wv = (const float*)d_in[8];
  const float* bv = (const float*)d_in[9];
  const float* Wl = (const float*)d_in[12];
  const float* bl = (const float*)d_in[13];
  const float* Wo = (const float*)d_in[14];
  const float* bo = (const float*)d_in[15];
  float* out = (float*)d_out;
  char* ws = (char*)d_ws;

  bf16* hb = (bf16*)(ws + 0);                    // 16 MB (reused as ybuf)
  bf16* lb = (bf16*)(ws + 16777216);             // 2 MB
  bf16* WqkvT = (bf16*)(ws + 18874368);          // 6 MB [3072][1024]
  bf16* WoT = (bf16*)(ws + 25165824);            // 2 MB
  bf16* WlT = (bf16*)(ws + 27262976);            // 256 KB
  float* bqkv = (float*)(ws + 27525120);         // 12 KB
  bf16* qcat = (bf16*)(ws + 27537408);           // 32 MB
  bf16* kcatc = (bf16*)(ws + 61091840);          // 32 MB
  bf16* vTc = (bf16*)(ws + 94646272);            // 16 MB
  int* pos_tab = (int*)(ws + 111423488);         // 32 KB
  int* srcrow = (int*)(ws + 111456256);          // 32 KB
  int* cnt = (int*)(ws + 111489024);             // 32 B
  bf16* ybuf = hb;

  // prep no longer depends on mask_scan; the tiny scan hides in prep's tail.
  prep<<<13572, 256, 0, stream>>>(h, l, Wq, Wk, Wv, Wo, Wl, bq, bk, bv, mask,
                                  hb, lb, WqkvT, WoT, WlT, bqkv, kcatc, vTc);
  mask_scan<<<8, 64, 0, stream>>>(mask, pos_tab, srcrow, cnt);

  gemm_qkv<<<dim3(64, 32), 256, 0, stream>>>(hb, WqkvT, lb, WlT, bqkv, bl,
                                             srcrow, cnt, pos_tab,
                                             qcat, kcatc, vTc);

  attn_kernel<<<1024, 512, 0, stream>>>(qcat, kcatc, vTc, cnt, ybuf);

  hipMemsetAsync(d_out, 0, (size_t)out_size * sizeof(float), stream);
  gemm_oproj<<<dim3(64, 8), 256, 0, stream>>>(ybuf, WoT, bo, out);
}